// Round 6
// baseline (562.055 us; speedup 1.0000x reference)
//
#include <hip/hip_runtime.h>
#include <cstdint>
#include <cstddef>

typedef __attribute__((ext_vector_type(4))) int i32x4;
typedef __bf16 bf16;
typedef __attribute__((ext_vector_type(8))) __bf16 bf16x8;
typedef __attribute__((ext_vector_type(4))) float f32x4;

#define BM 128
#define BN 128
#define BKB 128   // K-bytes per tile (i8) for the 128^2 fallback gemm
#define GROUP_M 16
#define GM256 4   // grouped-m for the 256^2 gemm
#define NXCD 8

__device__ __forceinline__ unsigned bf16_rne(float f) {
  unsigned u = __float_as_uint(f);
  unsigned r = 0x7FFFu + ((u >> 16) & 1u);
  return ((u + r) >> 16) & 0xFFFFu;
}
__device__ __forceinline__ unsigned pack2(float a, float b) {
  return bf16_rne(a) | (bf16_rne(b) << 16);
}
__device__ __forceinline__ int pack4i8(int a, int b, int c, int d) {
  return (a & 0xFF) | ((b & 0xFF) << 8) | ((c & 0xFF) << 16) | (d << 24);
}
__device__ __forceinline__ int q_i8(float v) {
  v = fminf(fmaxf(v, -127.0f), 127.0f);
  return __float2int_rn(v);
}

// ---------------- Phase 1 (merged): per-row int8 quantization ----------------
__global__ __launch_bounds__(256) void prep_kernel(
    const float* __restrict__ x, char* __restrict__ xq, float* __restrict__ xscale,
    int M,
    const int* __restrict__ q, const float* __restrict__ scale,
    const int* __restrict__ zp, char* __restrict__ wq, float* __restrict__ wscale,
    int K, int G) {
  __shared__ float red[4];
  const int b = blockIdx.x;
  const int tid = threadIdx.x;
  float f[16];

  if (b < M) {
    const float4* src = (const float4*)(x + (size_t)b * K);
#pragma unroll
    for (int i = 0; i < 4; ++i) {
      float4 v = src[tid + 256 * i];
      f[4 * i + 0] = v.x; f[4 * i + 1] = v.y;
      f[4 * i + 2] = v.z; f[4 * i + 3] = v.w;
    }
  } else {
    const int row = b - M;
    const int4* src = (const int4*)(q + (size_t)row * K);
    const float* srow = scale + (size_t)row * G;
    const int*   zrow = zp + (size_t)row * G;
#pragma unroll
    for (int i = 0; i < 4; ++i) {
      const int j = tid + 256 * i;
      const int g = j >> 5;            // 32 chunks per 128-elem group
      const float s = srow[g];
      const float nzs = -s * (float)zrow[g];   // f = q*s - z*s
      int4 qv = src[j];
      f[4 * i + 0] = fmaf((float)qv.x, s, nzs);
      f[4 * i + 1] = fmaf((float)qv.y, s, nzs);
      f[4 * i + 2] = fmaf((float)qv.z, s, nzs);
      f[4 * i + 3] = fmaf((float)qv.w, s, nzs);
    }
  }

  float m = 0.f;
#pragma unroll
  for (int j = 0; j < 16; ++j) m = fmaxf(m, fabsf(f[j]));
#pragma unroll
  for (int off = 32; off >= 1; off >>= 1) m = fmaxf(m, __shfl_xor(m, off));
  if ((tid & 63) == 0) red[tid >> 6] = m;
  __syncthreads();
  m = fmaxf(fmaxf(red[0], red[1]), fmaxf(red[2], red[3]));

  const float inv = m > 0.f ? 127.0f / m : 0.f;
  int pk[4];
#pragma unroll
  for (int i = 0; i < 4; ++i)
    pk[i] = pack4i8(q_i8(f[4 * i + 0] * inv), q_i8(f[4 * i + 1] * inv),
                    q_i8(f[4 * i + 2] * inv), q_i8(f[4 * i + 3] * inv));

  char* dst = (b < M) ? (xq + (size_t)b * K) : (wq + (size_t)(b - M) * K);
  int* dst_i32 = (int*)dst;
#pragma unroll
  for (int i = 0; i < 4; ++i) dst_i32[tid + 256 * i] = pk[i];

  if (tid == 0) {
    if (b < M) xscale[b] = m * (1.0f / 127.0f);
    else       wscale[b - M] = m * (1.0f / 127.0f);
  }
}

// ---------------- async global->LDS helper ----------------
typedef __attribute__((address_space(1))) void gas_void;
typedef __attribute__((address_space(3))) void las_void;

__device__ __forceinline__ void load_lds16(const void* g, void* l) {
  __builtin_amdgcn_global_load_lds((gas_void*)g, (las_void*)l, 16, 0, 0);
}

// ============ Phase 2 (R6): 256^2 compiler-scheduled i8 GEMM =================
// R5 post-mortem: halving LDS reads helped (261->240us, MfmaUtil 33%) but the
// barrier+lgkmcnt(0)+sched_barrier pinning serializes the read-window against
// the MFMA-window for ALL waves (read ~2000cy + MFMA ~2600cy add up to the
// ~6000cy/tile measured). R4 proved the global-load side is not the limiter.
//
// R6: REMOVE ALL INTRA-TILE PINS. Per 128B K-tile:
//   - stage tile t+1 -> nxt (8 global_load_lds per thread, issued up front)
//   - compute both K-slices of cur with PURE COMPILER SCHEDULING: hipcc emits
//     fine-grained lgkmcnt(N) interleaving ds_reads with MFMAs (m97 asm dump;
//     pinning costs ~40%, m141). LDS pipe and matrix pipe overlap both within
//     a wave and across the 2 waves/SIMD.
//   - ONE vmcnt(0) + ONE s_barrier + sched_barrier(0) per tile.
// 64 MFMA per barrier (vs 32 per 2 barriers in R5). Race-safety = R3's
// argument: writes into nxt are issued after the end-of-tile barrier at which
// every wave consumed its reads of nxt (MFMAs precede the barrier in program
// order and carry compiler lgkm deps); reads of t+1 start only after
// vmcnt(0)+barrier. The asm "memory" clobber keeps ds_reads from hoisting
// above the fence; sched_barrier(0) pins the tile boundary.
// Layout/swizzle/epilogue identical to verified R4/R5 (0 bank conflicts).

#define STAGE_A_H(buf, h, ktb) do {                                           \
    load_lds16(A + abase + (size_t)(ktb) + aoff0 + (size_t)(h) * 64 * K,      \
               &Al[buf][(h) * 8192 + dw]);                                    \
    load_lds16(A + abase + (size_t)(ktb) + aoff1 + (size_t)(h) * 64 * K,      \
               &Al[buf][16384 + (h) * 8192 + dw]);                            \
  } while (0)

#define STAGE_B_H(buf, h, ktb) do {                                           \
    load_lds16(Bw + bbase + (size_t)(ktb) + boff0 + (size_t)(h) * 32 * K,     \
               &Bl[buf][(h) * 16384 + dw]);                                   \
    load_lds16(Bw + bbase + (size_t)(ktb) + boff1 + (size_t)(h) * 32 * K,     \
               &Bl[buf][(h) * 16384 + 8192 + dw]);                            \
  } while (0)

__global__ __launch_bounds__(512, 2) void gemm_i8_256(
    const char* __restrict__ A,        // [M][K] i8
    const char* __restrict__ Bw,       // [N][K] i8
    const float* __restrict__ ascale,  // [M]
    const float* __restrict__ bscale,  // [N]
    const float* __restrict__ bias,    // [N]
    float* __restrict__ C,             // [M][N] fp32
    int M, int N, int K) {
  __shared__ __align__(16) char Al[2][256 * 128];
  __shared__ __align__(16) char Bl[2][256 * 128];
  const int tid  = threadIdx.x;
  const int wave = tid >> 6;
  const int lane = tid & 63;
  const int quad = lane >> 4;
  const int l16  = lane & 15;
  const int wq3  = wave & 3;
  const int wmb  = (wave >> 2) * 128;  // wave row base within tile (2 M-waves)
  const int wnb  = wq3 * 64;           // wave col base within tile (4 N-waves)

  // XCD-bijective chunked remap (launcher guarantees nblocks % 8 == 0)
  const int nbm = M / 256, nbn = N / 256;
  const int cpx = (nbm * nbn) / NXCD;
  const int swz = ((int)blockIdx.x % NXCD) * cpx + (int)blockIdx.x / NXCD;
  // grouped-m
  const int per_group = GM256 * nbn;
  const int gid = swz / per_group;
  const int rem = swz - gid * per_group;
  int gm = nbm - gid * GM256; if (gm > GM256) gm = GM256;
  const int bm = (gid * GM256 + (rem % gm)) * 256;
  const int bn = (rem / gm) * 256;

  // Per-thread staging invariants. r0 = tid>>3 in [0,64), kq = (tid&7)^(r0&7).
  // A (identity layout): load0 row = 64h + r0, load1 row = 128 + 64h + r0.
  // B (permuted layout): lds row p(n) = ((n>>5)&1)*128 + (n>>6)*32 + (n&31);
  //   load0 col n = (r0>>5)*64 + 32h + (r0&31), load1 col n = load0 + 128.
  const int r0 = tid >> 3;
  const int kq16 = (((tid & 7) ^ (r0 & 7)) * 16);
  const size_t aoff0 = (size_t)r0 * K + kq16;
  const size_t aoff1 = aoff0 + (size_t)128 * K;
  const size_t boff0 = (size_t)((r0 >> 5) * 64 + (r0 & 31)) * K + kq16;
  const size_t boff1 = boff0 + (size_t)128 * K;
  const int dw = wave * 1024;          // wave-uniform LDS dest base (bytes)
  const size_t abase = (size_t)bm * K;
  const size_t bbase = (size_t)bn * K;
  const int NT = K / 128;

  i32x4 acc[8][4];
#pragma unroll
  for (int i = 0; i < 8; ++i)
#pragma unroll
    for (int j = 0; j < 4; ++j)
      acc[i][j] = (i32x4){0, 0, 0, 0};

  // Prologue: stage tile0 fully -> buf0, drain, barrier.
  STAGE_A_H(0, 0, 0);
  STAGE_A_H(0, 1, 0);
  STAGE_B_H(0, 0, 0);
  STAGE_B_H(0, 1, 0);
  asm volatile("s_waitcnt vmcnt(0)" ::: "memory");
  __builtin_amdgcn_s_barrier();
  __builtin_amdgcn_sched_barrier(0);

  for (int t = 0; t < NT; ++t) {
    const int cur = t & 1;
    const int nxt = cur ^ 1;
    const int kt1 = (t + 1) * 128;

    if (t + 1 < NT) {
      STAGE_A_H(nxt, 0, kt1);
      STAGE_A_H(nxt, 1, kt1);
      STAGE_B_H(nxt, 0, kt1);
      STAGE_B_H(nxt, 1, kt1);
    }

    // Both K-slices of tile t, no pins: compiler interleaves ds_reads with
    // MFMAs via fine-grained lgkmcnt (m97-style scheduling).
#pragma unroll
    for (int ks = 0; ks < 2; ++ks) {
      i32x4 afr[8], bfr[4];
#pragma unroll
      for (int tm = 0; tm < 8; ++tm) {
        int row = wmb + tm * 16 + l16;
        int kq  = ks * 4 + quad;
        afr[tm] = *(const i32x4*)&Al[cur][(row * 8 + (kq ^ (row & 7))) * 16];
      }
#pragma unroll
      for (int j = 0; j < 4; ++j) {
        int p  = (j >> 1) * 128 + wq3 * 32 + (j & 1) * 16 + l16;
        int kq = ks * 4 + quad;
        bfr[j] = *(const i32x4*)&Bl[cur][(p * 8 + (kq ^ (p & 7))) * 16];
      }
#pragma unroll
      for (int tm = 0; tm < 8; ++tm)
#pragma unroll
        for (int j = 0; j < 4; ++j)
          acc[tm][j] = __builtin_amdgcn_mfma_i32_16x16x64_i8(
              afr[tm], bfr[j], acc[tm][j], 0, 0, 0);
    }

    asm volatile("s_waitcnt vmcnt(0)" ::: "memory");
    __builtin_amdgcn_s_barrier();
    __builtin_amdgcn_sched_barrier(0);
  }

  // Epilogue: D row = quad*4 + v, col = lane&15 (shape-determined).
  // acc[tm][j]: row offset tm*16, col offset j*16 of the wave's 128x64 tile.
#pragma unroll
  for (int tn = 0; tn < 4; ++tn) {
    int col = bn + wnb + tn * 16 + l16;
    float bv = bias[col];
    float ws = bscale[col];
#pragma unroll
    for (int tm = 0; tm < 8; ++tm) {
      int row0 = bm + wmb + tm * 16 + quad * 4;
#pragma unroll
      for (int v = 0; v < 4; ++v) {
        float val = ascale[row0 + v] * ws * (float)acc[tm][tn][v] + bv;
        __builtin_nontemporal_store(val, &C[(size_t)(row0 + v) * N + col]);
      }
    }
  }
}

// ---------------- Fallback A: 128^2 i8 GEMM (known-good) ---------------------
__global__ __launch_bounds__(256) void gemm_i8_kernel(
    const char* __restrict__ A, const char* __restrict__ Bw,
    const float* __restrict__ ascale, const float* __restrict__ bscale,
    const float* __restrict__ bias, float* __restrict__ C,
    int M, int N, int K) {
  __shared__ __align__(16) char Alds[BM * BKB];
  __shared__ __align__(16) char Blds[BN * BKB];
  const int tid  = threadIdx.x;
  const int wave = tid >> 6;
  const int lane = tid & 63;
  const int quad = lane >> 4;
  const int l16  = lane & 15;

  const int nbm = M / BM;
  const int nbn = N / BN;
  int flat = blockIdx.x;
  int per_group = GROUP_M * nbn;
  int gid = flat / per_group;
  int rem = flat - gid * per_group;
  int gm = nbm - gid * GROUP_M;
  if (gm > GROUP_M) gm = GROUP_M;
  const int bm = (gid * GROUP_M + (rem % gm)) * BM;
  const int bn = (rem / gm) * BN;

  const int wm = (wave & 1) * 64;
  const int wn = (wave >> 1) * 64;

  i32x4 acc[4][4];
#pragma unroll
  for (int i = 0; i < 4; ++i)
#pragma unroll
    for (int j = 0; j < 4; ++j)
      acc[i][j] = (i32x4){0, 0, 0, 0};

  for (int kt = 0; kt < K; kt += BKB) {
#pragma unroll
    for (int t = 0; t < 4; ++t) {
      int s0 = (wave * 4 + t) * 64;
      int s  = s0 + lane;
      int m  = s >> 3;
      int kq = (s & 7) ^ (m & 7);
      load_lds16(A  + (size_t)(bm + m) * K + kt + kq * 16, &Alds[s0 * 16]);
      load_lds16(Bw + (size_t)(bn + m) * K + kt + kq * 16, &Blds[s0 * 16]);
    }
    __syncthreads();

#pragma unroll
    for (int ks = 0; ks < 2; ++ks) {
      i32x4 af[4], bfr[4];
#pragma unroll
      for (int tm = 0; tm < 4; ++tm) {
        int m  = wm + tm * 16 + l16;
        int kq = ks * 4 + quad;
        af[tm] = *(const i32x4*)&Alds[(m * 8 + (kq ^ (m & 7))) * 16];
      }
#pragma unroll
      for (int tn = 0; tn < 4; ++tn) {
        int n  = wn + tn * 16 + l16;
        int kq = ks * 4 + quad;
        bfr[tn] = *(const i32x4*)&Blds[(n * 8 + (kq ^ (n & 7))) * 16];
      }
#pragma unroll
      for (int tm = 0; tm < 4; ++tm)
#pragma unroll
        for (int tn = 0; tn < 4; ++tn)
          acc[tm][tn] = __builtin_amdgcn_mfma_i32_16x16x64_i8(
              af[tm], bfr[tn], acc[tm][tn], 0, 0, 0);
    }
    __syncthreads();
  }

#pragma unroll
  for (int tn = 0; tn < 4; ++tn) {
    int col = bn + wn + tn * 16 + l16;
    float bv = bias[col];
    float ws = bscale[col];
#pragma unroll
    for (int tm = 0; tm < 4; ++tm) {
      int row0 = bm + wm + tm * 16 + quad * 4;
#pragma unroll
      for (int v = 0; v < 4; ++v) {
        float val = ascale[row0 + v] * ws * (float)acc[tm][tn][v] + bv;
        __builtin_nontemporal_store(val, &C[(size_t)(row0 + v) * N + col]);
      }
    }
  }
}

// ---------------- Fallback B: fused bf16 dequant GEMM (known-correct) --------
__global__ __launch_bounds__(256) void gemm_fused_kernel(
    const float* __restrict__ X, const int* __restrict__ Q,
    const float* __restrict__ scale, const int* __restrict__ zp,
    const float* __restrict__ bias, float* __restrict__ C,
    int M, int N, int K, int G) {
  __shared__ __align__(16) bf16 Alds[128 * 64];
  __shared__ __align__(16) bf16 Blds[128 * 64];
  const int tid  = threadIdx.x;
  const int wave = tid >> 6;
  const int lane = tid & 63;
  const int quad = lane >> 4;
  const int l16  = lane & 15;
  const int bm = blockIdx.y * 128;
  const int bn = blockIdx.x * 128;
  const int wm = (wave & 1) * 64;
  const int wn = (wave >> 1) * 64;

  f32x4 acc[4][4];
#pragma unroll
  for (int i = 0; i < 4; ++i)
#pragma unroll
    for (int j = 0; j < 4; ++j)
      acc[i][j] = (f32x4){0.f, 0.f, 0.f, 0.f};

  for (int kt = 0; kt < K; kt += 64) {
#pragma unroll
    for (int i = 0; i < 4; ++i) {
      int c = tid + i * 256;
      int m = c >> 3;
      int kq = (c & 7) ^ (m & 7);
      const float* src = X + (size_t)(bm + m) * K + kt + kq * 8;
      float4 v0 = *(const float4*)src;
      float4 v1 = *(const float4*)(src + 4);
      uint4 p;
      p.x = pack2(v0.x, v0.y); p.y = pack2(v0.z, v0.w);
      p.z = pack2(v1.x, v1.y); p.w = pack2(v1.z, v1.w);
      *(uint4*)&Alds[c * 8] = p;
    }
#pragma unroll
    for (int i = 0; i < 4; ++i) {
      int c = tid + i * 256;
      int n = c >> 3;
      int kq = (c & 7) ^ (n & 7);
      int kcol = kt + kq * 8;
      size_t row = (size_t)(bn + n);
      int g = kcol >> 7;
      float s = scale[row * G + g];
      float z = (float)zp[row * G + g];
      const int* src = Q + row * K + kcol;
      int4 q0 = *(const int4*)src;
      int4 q1 = *(const int4*)(src + 4);
      uint4 p;
      p.x = pack2(((float)q0.x - z) * s, ((float)q0.y - z) * s);
      p.y = pack2(((float)q0.z - z) * s, ((float)q0.w - z) * s);
      p.z = pack2(((float)q1.x - z) * s, ((float)q1.y - z) * s);
      p.w = pack2(((float)q1.z - z) * s, ((float)q1.w - z) * s);
      *(uint4*)&Blds[c * 8] = p;
    }
    __syncthreads();

#pragma unroll
    for (int ks = 0; ks < 2; ++ks) {
      bf16x8 af[4], bfr[4];
#pragma unroll
      for (int tm = 0; tm < 4; ++tm) {
        int m  = wm + tm * 16 + l16;
        int kq = ks * 4 + quad;
        af[tm] = *(const bf16x8*)&Alds[(m * 8 + (kq ^ (m & 7))) * 8];
      }
#pragma unroll
      for (int tn = 0; tn < 4; ++tn) {
        int n  = wn + tn * 16 + l16;
        int kq = ks * 4 + quad;
        bfr[tn] = *(const bf16x8*)&Blds[(n * 8 + (kq ^ (n & 7))) * 8];
      }
#pragma unroll
      for (int tm = 0; tm < 4; ++tm)
#pragma unroll
        for (int tn = 0; tn < 4; ++tn)
          acc[tm][tn] = __builtin_amdgcn_mfma_f32_16x16x32_bf16(
              af[tm], bfr[tn], acc[tm][tn], 0, 0, 0);
    }
    __syncthreads();
  }

#pragma unroll
  for (int tn = 0; tn < 4; ++tn) {
    int col = bn + wn + tn * 16 + l16;
    float bv = bias[col];
#pragma unroll
    for (int tm = 0; tm < 4; ++tm) {
      int row0 = bm + wm + tm * 16 + quad * 4;
#pragma unroll
      for (int v = 0; v < 4; ++v)
        C[(size_t)(row0 + v) * N + col] = acc[tm][tn][v] + bv;
    }
  }
}

extern "C" void kernel_launch(void* const* d_in, const int* in_sizes, int n_in,
                              void* d_out, int out_size, void* d_ws, size_t ws_size,
                              hipStream_t stream) {
  const float* x     = (const float*)d_in[0];
  const int*   qw    = (const int*)d_in[1];
  const float* scale = (const float*)d_in[2];
  const int*   zp    = (const int*)d_in[3];
  const float* bias  = (const float*)d_in[4];
  float* out = (float*)d_out;

  const int O = in_sizes[4];                 // 11008
  const int I = (int)(in_sizes[1] / O);      // 4096
  const int M = (int)(in_sizes[0] / I);      // 4096 (= B*S)
  const int G = in_sizes[2] / O;             // 32
  const int K = I, N = O;

  // ws layout: xq[M*K] i8 | xscale[M] f32 | wq[N*K] i8 | wscale[N] f32
  size_t off_xq = 0;
  size_t off_xs = off_xq + (size_t)M * K;
  size_t off_wq = (off_xs + (size_t)M * 4 + 255) & ~(size_t)255;
  size_t off_ws_ = off_wq + (size_t)N * K;
  size_t need   = ((off_ws_ + (size_t)N * 4 + 255) & ~(size_t)255);

  if (ws_size >= need && K == 4096) {
    char*  xq = (char*)d_ws + off_xq;
    float* xs = (float*)((char*)d_ws + off_xs);
    char*  wq = (char*)d_ws + off_wq;
    float* wsc = (float*)((char*)d_ws + off_ws_);

    prep_kernel<<<M + N, 256, 0, stream>>>(x, xq, xs, M, qw, scale, zp, wq, wsc, K, G);

    const int nb256 = (M / 256) * (N / 256);
    if ((M % 256) == 0 && (N % 256) == 0 && (nb256 % NXCD) == 0) {
      gemm_i8_256<<<nb256, 512, 0, stream>>>(xq, wq, xs, wsc, bias, out, M, N, K);
    } else {
      int nblocks = (M / BM) * (N / BN);
      gemm_i8_kernel<<<nblocks, 256, 0, stream>>>(xq, wq, xs, wsc, bias, out, M, N, K);
    }
  } else {
    dim3 gemm_grid((unsigned)(N / 128), (unsigned)(M / 128));
    gemm_fused_kernel<<<gemm_grid, 256, 0, stream>>>(x, qw, scale, zp, bias, out,
                                                     M, N, K, G);
  }
}

// Round 7
// 539.548 us; speedup vs baseline: 1.0417x; 1.0417x over previous
//
#include <hip/hip_runtime.h>
#include <cstdint>
#include <cstddef>

typedef __attribute__((ext_vector_type(4))) int i32x4;
typedef __bf16 bf16;
typedef __attribute__((ext_vector_type(8))) __bf16 bf16x8;
typedef __attribute__((ext_vector_type(4))) float f32x4;

#define BM 128
#define BN 128
#define BKB 128   // K-bytes per tile (i8) for the 128^2 fallback gemm
#define GROUP_M 16
#define GM256 4   // grouped-m for the 256^2 gemm
#define NXCD 8

__device__ __forceinline__ unsigned bf16_rne(float f) {
  unsigned u = __float_as_uint(f);
  unsigned r = 0x7FFFu + ((u >> 16) & 1u);
  return ((u + r) >> 16) & 0xFFFFu;
}
__device__ __forceinline__ unsigned pack2(float a, float b) {
  return bf16_rne(a) | (bf16_rne(b) << 16);
}
__device__ __forceinline__ int pack4i8(int a, int b, int c, int d) {
  return (a & 0xFF) | ((b & 0xFF) << 8) | ((c & 0xFF) << 16) | (d << 24);
}
__device__ __forceinline__ int q_i8(float v) {
  v = fminf(fmaxf(v, -127.0f), 127.0f);
  return __float2int_rn(v);
}

// ---------------- Phase 1 (R7): per-row int8 quantization --------------------
// blocks [0, M): x rows — 2-pass (load 16 f32/thread, block max, requant).
// blocks [M, M+N): W rows — ONE-PASS STREAMING via the analytic row bound:
//   w = (q - z_g)*s_g, q in [0,15]  =>  |w| <= B_row = max_g s_g*max(z_g,15-z_g).
//   P(true max < bound per group) = (15/16)^128 ~ 3e-4, so B ~ exact; bound
//   guarantees |wq| <= 127 (no clamp). Removes the 16-value register hold,
//   the shuffle/LDS reduce, the __syncthreads, and the load-all->store-all
//   serialization for 73% of prep traffic.
__global__ __launch_bounds__(256) void prep_kernel(
    const float* __restrict__ x, char* __restrict__ xq, float* __restrict__ xscale,
    int M,
    const int* __restrict__ q, const float* __restrict__ scale,
    const int* __restrict__ zp, char* __restrict__ wq, float* __restrict__ wscale,
    int K, int G) {
  __shared__ float red[4];
  const int b = blockIdx.x;
  const int tid = threadIdx.x;

  if (b >= M) {
    // ---- W path: streaming, no block reduce ----
    const int row = b - M;
    const float* srow = scale + (size_t)row * G;
    const int*   zrow = zp + (size_t)row * G;
    // Analytic row bound: lanes duplicate g over the two 32-lane halves;
    // xor-reduce(16..1) completes within each half. No syncthreads needed.
    const int lane = tid & 63;
    const int g0 = lane & 31;
    const float s0 = srow[g0];
    const float z0 = (float)zrow[g0];
    float bnd = s0 * fmaxf(z0, 15.0f - z0);
#pragma unroll
    for (int off = 16; off >= 1; off >>= 1)
      bnd = fmaxf(bnd, __shfl_xor(bnd, off));
    const float inv = 127.0f / bnd;        // bnd >= 7.5*s > 0 always
    const int4* src = (const int4*)(q + (size_t)row * K);
    int* dst = (int*)(wq + (size_t)row * K);
#pragma unroll
    for (int i = 0; i < 4; ++i) {
      const int j = tid + 256 * i;         // 16B chunk index; elems [4j,4j+4)
      const int g = j >> 5;                // group = 4j/128
      const float fs = srow[g] * inv;
      const float fo = -(float)zrow[g] * srow[g] * inv;
      int4 qv = src[j];
      dst[j] = pack4i8(__float2int_rn(fmaf((float)qv.x, fs, fo)),
                       __float2int_rn(fmaf((float)qv.y, fs, fo)),
                       __float2int_rn(fmaf((float)qv.z, fs, fo)),
                       __float2int_rn(fmaf((float)qv.w, fs, fo)));
    }
    if (tid == 0) wscale[row] = bnd * (1.0f / 127.0f);
    return;
  }

  // ---- x path: 2-pass (true row max) ----
  float f[16];
  const float4* src = (const float4*)(x + (size_t)b * K);
#pragma unroll
  for (int i = 0; i < 4; ++i) {
    float4 v = src[tid + 256 * i];
    f[4 * i + 0] = v.x; f[4 * i + 1] = v.y;
    f[4 * i + 2] = v.z; f[4 * i + 3] = v.w;
  }

  float m = 0.f;
#pragma unroll
  for (int j = 0; j < 16; ++j) m = fmaxf(m, fabsf(f[j]));
#pragma unroll
  for (int off = 32; off >= 1; off >>= 1) m = fmaxf(m, __shfl_xor(m, off));
  if ((tid & 63) == 0) red[tid >> 6] = m;
  __syncthreads();
  m = fmaxf(fmaxf(red[0], red[1]), fmaxf(red[2], red[3]));

  const float inv = m > 0.f ? 127.0f / m : 0.f;
  int pk[4];
#pragma unroll
  for (int i = 0; i < 4; ++i)
    pk[i] = pack4i8(q_i8(f[4 * i + 0] * inv), q_i8(f[4 * i + 1] * inv),
                    q_i8(f[4 * i + 2] * inv), q_i8(f[4 * i + 3] * inv));

  int* dst_i32 = (int*)(xq + (size_t)b * K);
#pragma unroll
  for (int i = 0; i < 4; ++i) dst_i32[tid + 256 * i] = pk[i];

  if (tid == 0) xscale[b] = m * (1.0f / 127.0f);
}

// ---------------- async global->LDS helper ----------------
typedef __attribute__((address_space(1))) void gas_void;
typedef __attribute__((address_space(3))) void las_void;

__device__ __forceinline__ void load_lds16(const void* g, void* l) {
  __builtin_amdgcn_global_load_lds((gas_void*)g, (las_void*)l, 16, 0, 0);
}

// ============ Phase 2 (R7 = R5, best measured): 256^2 2-phase i8 GEMM ========
// Schedule ledger: R3 quadrant+drain 261us | R4 quadrant+counted 270 | R5
// K-slice 2-phase+drain 240 (BEST) | R6 no-pins 254. Reverting to R5 verbatim.
// Per tile: ph1 = {12 ds_read + 32 MFMA (ks=0), stage all of t+1 -> nxt},
// ph2 = {ks=1, vmcnt(0)}. Race-safe: writes into nxt issue after the
// end-of-tile barrier at which every wave's reads of nxt drained (lgkmcnt(0)
// precedes MFMAs; barrier follows); reads of t+1 start after vmcnt(0)+barrier.

#define STAGE_A_H(buf, h, ktb) do {                                           \
    load_lds16(A + abase + (size_t)(ktb) + aoff0 + (size_t)(h) * 64 * K,      \
               &Al[buf][(h) * 8192 + dw]);                                    \
    load_lds16(A + abase + (size_t)(ktb) + aoff1 + (size_t)(h) * 64 * K,      \
               &Al[buf][16384 + (h) * 8192 + dw]);                            \
  } while (0)

#define STAGE_B_H(buf, h, ktb) do {                                           \
    load_lds16(Bw + bbase + (size_t)(ktb) + boff0 + (size_t)(h) * 32 * K,     \
               &Bl[buf][(h) * 16384 + dw]);                                   \
    load_lds16(Bw + bbase + (size_t)(ktb) + boff1 + (size_t)(h) * 32 * K,     \
               &Bl[buf][(h) * 16384 + 8192 + dw]);                            \
  } while (0)

#define PHASE2(CUR, KS, STAGE_STMT, WAIT_STMT) do {                           \
    i32x4 afr[8], bfr[4];                                                     \
    _Pragma("unroll")                                                         \
    for (int tm = 0; tm < 8; ++tm) {                                          \
      int row = wmb + tm * 16 + l16;                                          \
      int kq  = (KS) * 4 + quad;                                              \
      afr[tm] = *(const i32x4*)&Al[CUR][(row * 8 + (kq ^ (row & 7))) * 16];   \
    }                                                                         \
    _Pragma("unroll")                                                         \
    for (int j = 0; j < 4; ++j) {                                             \
      int p  = (j >> 1) * 128 + wq3 * 32 + (j & 1) * 16 + l16;                \
      int kq = (KS) * 4 + quad;                                               \
      bfr[j] = *(const i32x4*)&Bl[CUR][(p * 8 + (kq ^ (p & 7))) * 16];        \
    }                                                                         \
    STAGE_STMT;                                                               \
    __builtin_amdgcn_s_barrier();                                             \
    asm volatile("s_waitcnt lgkmcnt(0)" ::: "memory");                        \
    __builtin_amdgcn_sched_barrier(0);                                        \
    __builtin_amdgcn_s_setprio(1);                                            \
    _Pragma("unroll")                                                         \
    for (int tm = 0; tm < 8; ++tm) {                                          \
      _Pragma("unroll")                                                       \
      for (int j = 0; j < 4; ++j) {                                           \
        acc[tm][j] = __builtin_amdgcn_mfma_i32_16x16x64_i8(                   \
            afr[tm], bfr[j], acc[tm][j], 0, 0, 0);                            \
      }                                                                       \
    }                                                                         \
    __builtin_amdgcn_s_setprio(0);                                            \
    WAIT_STMT;                                                                \
    __builtin_amdgcn_s_barrier();                                             \
    __builtin_amdgcn_sched_barrier(0);                                        \
  } while (0)

__global__ __launch_bounds__(512) void gemm_i8_256(
    const char* __restrict__ A,        // [M][K] i8
    const char* __restrict__ Bw,       // [N][K] i8
    const float* __restrict__ ascale,  // [M]
    const float* __restrict__ bscale,  // [N]
    const float* __restrict__ bias,    // [N]
    float* __restrict__ C,             // [M][N] fp32
    int M, int N, int K) {
  __shared__ __align__(16) char Al[2][256 * 128];
  __shared__ __align__(16) char Bl[2][256 * 128];
  const int tid  = threadIdx.x;
  const int wave = tid >> 6;
  const int lane = tid & 63;
  const int quad = lane >> 4;
  const int l16  = lane & 15;
  const int wq3  = wave & 3;
  const int wmb  = (wave >> 2) * 128;  // wave row base within tile (2 M-waves)
  const int wnb  = wq3 * 64;           // wave col base within tile (4 N-waves)

  // XCD-bijective chunked remap (launcher guarantees nblocks % 8 == 0)
  const int nbm = M / 256, nbn = N / 256;
  const int cpx = (nbm * nbn) / NXCD;
  const int swz = ((int)blockIdx.x % NXCD) * cpx + (int)blockIdx.x / NXCD;
  // grouped-m
  const int per_group = GM256 * nbn;
  const int gid = swz / per_group;
  const int rem = swz - gid * per_group;
  int gm = nbm - gid * GM256; if (gm > GM256) gm = GM256;
  const int bm = (gid * GM256 + (rem % gm)) * 256;
  const int bn = (rem / gm) * 256;

  // Per-thread staging invariants. r0 = tid>>3 in [0,64), kq = (tid&7)^(r0&7).
  // A (identity layout): load0 row = 64h + r0, load1 row = 128 + 64h + r0.
  // B (permuted layout): lds row p(n) = ((n>>5)&1)*128 + (n>>6)*32 + (n&31);
  //   load0 col n = (r0>>5)*64 + 32h + (r0&31), load1 col n = load0 + 128.
  const int r0 = tid >> 3;
  const int kq16 = (((tid & 7) ^ (r0 & 7)) * 16);
  const size_t aoff0 = (size_t)r0 * K + kq16;
  const size_t aoff1 = aoff0 + (size_t)128 * K;
  const size_t boff0 = (size_t)((r0 >> 5) * 64 + (r0 & 31)) * K + kq16;
  const size_t boff1 = boff0 + (size_t)128 * K;
  const int dw = wave * 1024;          // wave-uniform LDS dest base (bytes)
  const size_t abase = (size_t)bm * K;
  const size_t bbase = (size_t)bn * K;
  const int NT = K / 128;

  i32x4 acc[8][4];
#pragma unroll
  for (int i = 0; i < 8; ++i)
#pragma unroll
    for (int j = 0; j < 4; ++j)
      acc[i][j] = (i32x4){0, 0, 0, 0};

  // Prologue: stage tile0 fully -> buf0, drain, barrier.
  STAGE_A_H(0, 0, 0);
  STAGE_A_H(0, 1, 0);
  STAGE_B_H(0, 0, 0);
  STAGE_B_H(0, 1, 0);
  asm volatile("s_waitcnt vmcnt(0)" ::: "memory");
  __builtin_amdgcn_s_barrier();
  __builtin_amdgcn_sched_barrier(0);

  for (int t = 0; t < NT; ++t) {
    const int cur = t & 1;
    const int nxt = cur ^ 1;
    const int kt1 = (t + 1) * 128;
    const bool s1 = (t + 1) < NT;

    PHASE2(cur, 0,
           {
             if (s1) {
               STAGE_A_H(nxt, 0, kt1);
               STAGE_A_H(nxt, 1, kt1);
               STAGE_B_H(nxt, 0, kt1);
               STAGE_B_H(nxt, 1, kt1);
             }
           },
           {});
    PHASE2(cur, 1, {},
           { asm volatile("s_waitcnt vmcnt(0)" ::: "memory"); });
  }

  // Epilogue: D row = quad*4 + v, col = lane&15 (shape-determined).
  // acc[tm][j]: row offset tm*16, col offset j*16 of the wave's 128x64 tile.
#pragma unroll
  for (int tn = 0; tn < 4; ++tn) {
    int col = bn + wnb + tn * 16 + l16;
    float bv = bias[col];
    float ws = bscale[col];
#pragma unroll
    for (int tm = 0; tm < 8; ++tm) {
      int row0 = bm + wmb + tm * 16 + quad * 4;
#pragma unroll
      for (int v = 0; v < 4; ++v) {
        float val = ascale[row0 + v] * ws * (float)acc[tm][tn][v] + bv;
        __builtin_nontemporal_store(val, &C[(size_t)(row0 + v) * N + col]);
      }
    }
  }
}

// ---------------- Fallback A: 128^2 i8 GEMM (known-good) ---------------------
__global__ __launch_bounds__(256) void gemm_i8_kernel(
    const char* __restrict__ A, const char* __restrict__ Bw,
    const float* __restrict__ ascale, const float* __restrict__ bscale,
    const float* __restrict__ bias, float* __restrict__ C,
    int M, int N, int K) {
  __shared__ __align__(16) char Alds[BM * BKB];
  __shared__ __align__(16) char Blds[BN * BKB];
  const int tid  = threadIdx.x;
  const int wave = tid >> 6;
  const int lane = tid & 63;
  const int quad = lane >> 4;
  const int l16  = lane & 15;

  const int nbm = M / BM;
  const int nbn = N / BN;
  int flat = blockIdx.x;
  int per_group = GROUP_M * nbn;
  int gid = flat / per_group;
  int rem = flat - gid * per_group;
  int gm = nbm - gid * GROUP_M;
  if (gm > GROUP_M) gm = GROUP_M;
  const int bm = (gid * GROUP_M + (rem % gm)) * BM;
  const int bn = (rem / gm) * BN;

  const int wm = (wave & 1) * 64;
  const int wn = (wave >> 1) * 64;

  i32x4 acc[4][4];
#pragma unroll
  for (int i = 0; i < 4; ++i)
#pragma unroll
    for (int j = 0; j < 4; ++j)
      acc[i][j] = (i32x4){0, 0, 0, 0};

  for (int kt = 0; kt < K; kt += BKB) {
#pragma unroll
    for (int t = 0; t < 4; ++t) {
      int s0 = (wave * 4 + t) * 64;
      int s  = s0 + lane;
      int m  = s >> 3;
      int kq = (s & 7) ^ (m & 7);
      load_lds16(A  + (size_t)(bm + m) * K + kt + kq * 16, &Alds[s0 * 16]);
      load_lds16(Bw + (size_t)(bn + m) * K + kt + kq * 16, &Blds[s0 * 16]);
    }
    __syncthreads();

#pragma unroll
    for (int ks = 0; ks < 2; ++ks) {
      i32x4 af[4], bfr[4];
#pragma unroll
      for (int tm = 0; tm < 4; ++tm) {
        int m  = wm + tm * 16 + l16;
        int kq = ks * 4 + quad;
        af[tm] = *(const i32x4*)&Alds[(m * 8 + (kq ^ (m & 7))) * 16];
      }
#pragma unroll
      for (int tn = 0; tn < 4; ++tn) {
        int n  = wn + tn * 16 + l16;
        int kq = ks * 4 + quad;
        bfr[tn] = *(const i32x4*)&Blds[(n * 8 + (kq ^ (n & 7))) * 16];
      }
#pragma unroll
      for (int tm = 0; tm < 4; ++tm)
#pragma unroll
        for (int tn = 0; tn < 4; ++tn)
          acc[tm][tn] = __builtin_amdgcn_mfma_i32_16x16x64_i8(
              af[tm], bfr[tn], acc[tm][tn], 0, 0, 0);
    }
    __syncthreads();
  }

#pragma unroll
  for (int tn = 0; tn < 4; ++tn) {
    int col = bn + wn + tn * 16 + l16;
    float bv = bias[col];
    float ws = bscale[col];
#pragma unroll
    for (int tm = 0; tm < 4; ++tm) {
      int row0 = bm + wm + tm * 16 + quad * 4;
#pragma unroll
      for (int v = 0; v < 4; ++v) {
        float val = ascale[row0 + v] * ws * (float)acc[tm][tn][v] + bv;
        __builtin_nontemporal_store(val, &C[(size_t)(row0 + v) * N + col]);
      }
    }
  }
}

// ---------------- Fallback B: fused bf16 dequant GEMM (known-correct) --------
__global__ __launch_bounds__(256) void gemm_fused_kernel(
    const float* __restrict__ X, const int* __restrict__ Q,
    const float* __restrict__ scale, const int* __restrict__ zp,
    const float* __restrict__ bias, float* __restrict__ C,
    int M, int N, int K, int G) {
  __shared__ __align__(16) bf16 Alds[128 * 64];
  __shared__ __align__(16) bf16 Blds[128 * 64];
  const int tid  = threadIdx.x;
  const int wave = tid >> 6;
  const int lane = tid & 63;
  const int quad = lane >> 4;
  const int l16  = lane & 15;
  const int bm = blockIdx.y * 128;
  const int bn = blockIdx.x * 128;
  const int wm = (wave & 1) * 64;
  const int wn = (wave >> 1) * 64;

  f32x4 acc[4][4];
#pragma unroll
  for (int i = 0; i < 4; ++i)
#pragma unroll
    for (int j = 0; j < 4; ++j)
      acc[i][j] = (f32x4){0.f, 0.f, 0.f, 0.f};

  for (int kt = 0; kt < K; kt += 64) {
#pragma unroll
    for (int i = 0; i < 4; ++i) {
      int c = tid + i * 256;
      int m = c >> 3;
      int kq = (c & 7) ^ (m & 7);
      const float* src = X + (size_t)(bm + m) * K + kt + kq * 8;
      float4 v0 = *(const float4*)src;
      float4 v1 = *(const float4*)(src + 4);
      uint4 p;
      p.x = pack2(v0.x, v0.y); p.y = pack2(v0.z, v0.w);
      p.z = pack2(v1.x, v1.y); p.w = pack2(v1.z, v1.w);
      *(uint4*)&Alds[c * 8] = p;
    }
#pragma unroll
    for (int i = 0; i < 4; ++i) {
      int c = tid + i * 256;
      int n = c >> 3;
      int kq = (c & 7) ^ (n & 7);
      int kcol = kt + kq * 8;
      size_t row = (size_t)(bn + n);
      int g = kcol >> 7;
      float s = scale[row * G + g];
      float z = (float)zp[row * G + g];
      const int* src = Q + row * K + kcol;
      int4 q0 = *(const int4*)src;
      int4 q1 = *(const int4*)(src + 4);
      uint4 p;
      p.x = pack2(((float)q0.x - z) * s, ((float)q0.y - z) * s);
      p.y = pack2(((float)q0.z - z) * s, ((float)q0.w - z) * s);
      p.z = pack2(((float)q1.x - z) * s, ((float)q1.y - z) * s);
      p.w = pack2(((float)q1.z - z) * s, ((float)q1.w - z) * s);
      *(uint4*)&Blds[c * 8] = p;
    }
    __syncthreads();

#pragma unroll
    for (int ks = 0; ks < 2; ++ks) {
      bf16x8 af[4], bfr[4];
#pragma unroll
      for (int tm = 0; tm < 4; ++tm) {
        int m  = wm + tm * 16 + l16;
        int kq = ks * 4 + quad;
        af[tm] = *(const bf16x8*)&Alds[(m * 8 + (kq ^ (m & 7))) * 8];
      }
#pragma unroll
      for (int tn = 0; tn < 4; ++tn) {
        int n  = wn + tn * 16 + l16;
        int kq = ks * 4 + quad;
        bfr[tn] = *(const bf16x8*)&Blds[(n * 8 + (kq ^ (n & 7))) * 8];
      }
#pragma unroll
      for (int tm = 0; tm < 4; ++tm)
#pragma unroll
        for (int tn = 0; tn < 4; ++tn)
          acc[tm][tn] = __builtin_amdgcn_mfma_f32_16x16x32_bf16(
              af[tm], bfr[tn], acc[tm][tn], 0, 0, 0);
    }
    __syncthreads();
  }

#pragma unroll
  for (int tn = 0; tn < 4; ++tn) {
    int col = bn + wn + tn * 16 + l16;
    float bv = bias[col];
#pragma unroll
    for (int tm = 0; tm < 4; ++tm) {
      int row0 = bm + wm + tm * 16 + quad * 4;
#pragma unroll
      for (int v = 0; v < 4; ++v)
        C[(size_t)(row0 + v) * N + col] = acc[tm][tn][v] + bv;
    }
  }
}

extern "C" void kernel_launch(void* const* d_in, const int* in_sizes, int n_in,
                              void* d_out, int out_size, void* d_ws, size_t ws_size,
                              hipStream_t stream) {
  const float* x     = (const float*)d_in[0];
  const int*   qw    = (const int*)d_in[1];
  const float* scale = (const float*)d_in[2];
  const int*   zp    = (const int*)d_in[3];
  const float* bias  = (const float*)d_in[4];
  float* out = (float*)d_out;

  const int O = in_sizes[4];                 // 11008
  const int I = (int)(in_sizes[1] / O);      // 4096
  const int M = (int)(in_sizes[0] / I);      // 4096 (= B*S)
  const int G = in_sizes[2] / O;             // 32
  const int K = I, N = O;

  // ws layout: xq[M*K] i8 | xscale[M] f32 | wq[N*K] i8 | wscale[N] f32
  size_t off_xq = 0;
  size_t off_xs = off_xq + (size_t)M * K;
  size_t off_wq = (off_xs + (size_t)M * 4 + 255) & ~(size_t)255;
  size_t off_ws_ = off_wq + (size_t)N * K;
  size_t need   = ((off_ws_ + (size_t)N * 4 + 255) & ~(size_t)255);

  if (ws_size >= need && K == 4096) {
    char*  xq = (char*)d_ws + off_xq;
    float* xs = (float*)((char*)d_ws + off_xs);
    char*  wq = (char*)d_ws + off_wq;
    float* wsc = (float*)((char*)d_ws + off_ws_);

    prep_kernel<<<M + N, 256, 0, stream>>>(x, xq, xs, M, qw, scale, zp, wq, wsc, K, G);

    const int nb256 = (M / 256) * (N / 256);
    if ((M % 256) == 0 && (N % 256) == 0 && (nb256 % NXCD) == 0) {
      gemm_i8_256<<<nb256, 512, 0, stream>>>(xq, wq, xs, wsc, bias, out, M, N, K);
    } else {
      int nblocks = (M / BM) * (N / BN);
      gemm_i8_kernel<<<nblocks, 256, 0, stream>>>(xq, wq, xs, wsc, bias, out, M, N, K);
    }
  } else {
    dim3 gemm_grid((unsigned)(N / 128), (unsigned)(M / 128));
    gemm_fused_kernel<<<gemm_grid, 256, 0, stream>>>(x, qw, scale, zp, bias, out,
                                                     M, N, K, G);
  }
}